// Round 1
// 669.149 us; speedup vs baseline: 1.0225x; 1.0225x over previous
//
#include <hip/hip_runtime.h>
#include <stdint.h>

typedef unsigned short u16;
typedef u16 us8 __attribute__((ext_vector_type(8)));
typedef uint32_t u32x8 __attribute__((ext_vector_type(8)));
typedef __bf16 bf16x8 __attribute__((ext_vector_type(8)));
typedef float f32x4 __attribute__((ext_vector_type(4)));

#define BB 16
#define TT 2048
#define HH 1024
#define MM 32768   // B*T
#define NN 3072    // H + 2H
#define KK 1024
#define NT 16      // K-tiles of 64

__device__ __forceinline__ float b2f(u16 u) {
    union { uint32_t i; float f; } v; v.i = ((uint32_t)u) << 16; return v.f;
}
__device__ __forceinline__ u16 f2b(float f) {
    union { uint32_t i; float f; } v; v.f = f;
    uint32_t r = v.i + 0x7fffu + ((v.i >> 16) & 1u);
    return (u16)(r >> 16);
}
__device__ __forceinline__ float sigm(float z) {
    return 1.f / (1.f + __expf(-z));
}
__device__ __forceinline__ void load_lds16(const u16* g, u16* l) {
    __builtin_amdgcn_global_load_lds(
        (const __attribute__((address_space(1))) void*)g,
        (__attribute__((address_space(3))) void*)l, 16, 0, 0);
}
__device__ __forceinline__ f32x4 mf(bf16x8 a, bf16x8 b, f32x4 c) {
    return __builtin_amdgcn_mfma_f32_16x16x32_bf16(a, b, c, 0, 0, 0);
}

// ---- K0: x fp32 -> bf16, [W_lt;W_g] fp32 -> bf16 (merged) ----------------
__global__ __launch_bounds__(256) void k_cvt(const float* __restrict__ x,
                                             const float* __restrict__ wlt,
                                             const float* __restrict__ wg,
                                             u16* __restrict__ xb,
                                             u16* __restrict__ wb) {
    long i = (long)(blockIdx.x * 256 + threadIdx.x) * 8;
    const float* s;
    u16* o;
    if (i < 33554432L) { s = x + i; o = xb + i; }
    else {
        long j = i - 33554432L;
        s = (j < 1048576L) ? (wlt + j) : (wg + (j - 1048576L));
        o = wb + j;
    }
    float4 a = *(const float4*)(s);
    float4 b = *(const float4*)(s + 4);
    us8 r;
    r[0] = f2b(a.x); r[1] = f2b(a.y); r[2] = f2b(a.z); r[3] = f2b(a.w);
    r[4] = f2b(b.x); r[5] = f2b(b.y); r[6] = f2b(b.z); r[7] = f2b(b.w);
    *(us8*)o = r;
}

// ---- K1: Y[32768,3072] = Xb @ Wb^T  (256x256 8-phase, T2+T3+T4+T5) -------
// 512 thr = 8 waves (2M x 4N); BK=64; LDS 128 KiB dbuf; per-wave C 128x64.
// LDS layout A: [buf][mh][wm][64 rows][64 cols], B: [buf][nh][wn][32][64];
// bank swizzle: 16B-slot s_lds = s_log ^ (row & 7), applied on the GLOBAL
// source address at stage time (linear global_load_lds dest) and on the
// ds_read address at use time (rule #21: both-sides-or-neither).
__global__ __launch_bounds__(512, 2) void k_gemm(const u16* __restrict__ A,
                                                 const u16* __restrict__ W,
                                                 u16* __restrict__ Y) {
    __shared__ u16 As[2 * 16384];
    __shared__ u16 Bs[2 * 16384];
    const int tid = threadIdx.x;
    const int lane = tid & 63;
    const int w = tid >> 6;        // 0..7
    const int wm = w >> 2;         // 0..1
    const int wn = w & 3;          // 0..3
    const int q = lane >> 4;
    const int l16 = lane & 15;
    const int bx = blockIdx.x;     // N tile (12)
    const int by = blockIdx.y;     // M tile (128)

    // ---- staging: per-thread pre-swizzled global source, linear LDS dest.
    // round r of A covers rows {(r&1)*128 + (r>>1)*64 + tid>>3}, B covers
    // rows {(r&1)*128 + (r>>1)*32 + (tid>>8)*64 + (tid>>3)&31}; the 16B
    // slot tid&7 holds logical slot (tid&7)^((tid>>3)&7).
    const int slog = ((tid & 7) ^ ((tid >> 3) & 7)) << 3;
    const u16* aS = A + (size_t)(by * 256 + (tid >> 3)) * KK + slog;
    const u16* bS = W + (size_t)(bx * 256 + ((tid >> 8) << 6) + ((tid >> 3) & 31)) * KK + slog;
    u16* aD = As + w * 512;
    u16* bD = Bs + w * 512;

    // prologue: stage kt0 -> buf0 (first 8 issued), kt1 -> buf1 (next 8)
    load_lds16(aS,                aD);
    load_lds16(aS + 128 * KK,     aD + 4096);
    load_lds16(aS + 64 * KK,      aD + 8192);
    load_lds16(aS + 192 * KK,     aD + 12288);
    load_lds16(bS,                bD);
    load_lds16(bS + 128 * KK,     bD + 4096);
    load_lds16(bS + 32 * KK,      bD + 8192);
    load_lds16(bS + 160 * KK,     bD + 12288);
    load_lds16(aS + 64,           aD + 16384);
    load_lds16(aS + 64 + 128*KK,  aD + 16384 + 4096);
    load_lds16(aS + 64 + 64*KK,   aD + 16384 + 8192);
    load_lds16(aS + 64 + 192*KK,  aD + 16384 + 12288);
    load_lds16(bS + 64,           bD + 16384);
    load_lds16(bS + 64 + 128*KK,  bD + 16384 + 4096);
    load_lds16(bS + 64 + 32*KK,   bD + 16384 + 8192);
    load_lds16(bS + 64 + 160*KK,  bD + 16384 + 12288);

    // ---- ds_read lane bases (swizzled): slot(ks) = ((ks<<2)|q) ^ (l16&7)
    const int key = l16 & 7;
    const int sA0 = ((q ^ key) << 3);
    const int sA1 = (((q ^ key) ^ 4) << 3);
    const int aB0 = wm * 4096 + l16 * 64 + sA0;
    const int aB1 = wm * 4096 + l16 * 64 + sA1;
    const int bB0 = wn * 2048 + l16 * 64 + sA0;
    const int bB1 = wn * 2048 + l16 * 64 + sA1;

    f32x4 zero = {0.f, 0.f, 0.f, 0.f};
    f32x4 acc[8][4];
#pragma unroll
    for (int i = 0; i < 8; ++i)
#pragma unroll
        for (int j = 0; j < 4; ++j) acc[i][j] = zero;
    bf16x8 aR[4][2], bR[4][2];

    asm volatile("s_waitcnt vmcnt(8)" ::: "memory");   // kt0 landed; kt1 in flight
    __builtin_amdgcn_sched_barrier(0);
    __builtin_amdgcn_s_barrier();
    asm volatile("" ::: "memory");

    for (int kt = 0; kt < NT; ++kt) {
        const int cb = (kt & 1) << 14;   // buffer byte-layout offset in u16
        const int kc = (kt + 2) << 6;    // staged K-column for kt+2
        // ================= phase 1: ds A-half0 + all B; MFMA q(0,0) =======
#pragma unroll
        for (int i = 0; i < 4; ++i) {
            aR[i][0] = *(const bf16x8*)&As[cb + i * 1024 + aB0];
            aR[i][1] = *(const bf16x8*)&As[cb + i * 1024 + aB1];
        }
#pragma unroll
        for (int f = 0; f < 4; ++f) {
            bR[f][0] = *(const bf16x8*)&Bs[cb + (f >> 1) * 8192 + (f & 1) * 1024 + bB0];
            bR[f][1] = *(const bf16x8*)&Bs[cb + (f >> 1) * 8192 + (f & 1) * 1024 + bB1];
        }
        asm volatile("" ::: "memory");
        __builtin_amdgcn_s_barrier();
        asm volatile("s_waitcnt lgkmcnt(0)" ::: "memory");
        __builtin_amdgcn_sched_barrier(0);
        __builtin_amdgcn_s_setprio(1);
#pragma unroll
        for (int i = 0; i < 4; ++i)
#pragma unroll
            for (int f = 0; f < 2; ++f) {
                acc[i][f] = mf(aR[i][0], bR[f][0], acc[i][f]);
                acc[i][f] = mf(aR[i][1], bR[f][1], acc[i][f]);
            }
        __builtin_amdgcn_s_setprio(0);
        asm volatile("" ::: "memory");
        __builtin_amdgcn_s_barrier();
        asm volatile("" ::: "memory");
        // ================= phase 2: stage A-h0+B of kt+2; MFMA q(0,1) =====
        if (kt < NT - 2) {
            load_lds16(aS + kc,            aD + cb);
            load_lds16(aS + kc + 128*KK,   aD + cb + 4096);
            load_lds16(bS + kc,            bD + cb);
            load_lds16(bS + kc + 128*KK,   bD + cb + 4096);
            load_lds16(bS + kc + 32*KK,    bD + cb + 8192);
            load_lds16(bS + kc + 160*KK,   bD + cb + 12288);
        }
        asm volatile("" ::: "memory");
        __builtin_amdgcn_s_barrier();
        __builtin_amdgcn_s_setprio(1);
#pragma unroll
        for (int i = 0; i < 4; ++i)
#pragma unroll
            for (int f = 2; f < 4; ++f) {
                acc[i][f] = mf(aR[i][0], bR[f][0], acc[i][f]);
                acc[i][f] = mf(aR[i][1], bR[f][1], acc[i][f]);
            }
        __builtin_amdgcn_s_setprio(0);
        asm volatile("" ::: "memory");
        __builtin_amdgcn_s_barrier();
        asm volatile("" ::: "memory");
        // ================= phase 3: ds A-half1; MFMA q(1,0) ===============
#pragma unroll
        for (int i = 0; i < 4; ++i) {
            aR[i][0] = *(const bf16x8*)&As[cb + 8192 + i * 1024 + aB0];
            aR[i][1] = *(const bf16x8*)&As[cb + 8192 + i * 1024 + aB1];
        }
        asm volatile("" ::: "memory");
        __builtin_amdgcn_s_barrier();
        asm volatile("s_waitcnt lgkmcnt(0)" ::: "memory");
        __builtin_amdgcn_sched_barrier(0);
        __builtin_amdgcn_s_setprio(1);
#pragma unroll
        for (int i = 0; i < 4; ++i)
#pragma unroll
            for (int f = 0; f < 2; ++f) {
                acc[4 + i][f] = mf(aR[i][0], bR[f][0], acc[4 + i][f]);
                acc[4 + i][f] = mf(aR[i][1], bR[f][1], acc[4 + i][f]);
            }
        __builtin_amdgcn_s_setprio(0);
        asm volatile("" ::: "memory");
        __builtin_amdgcn_s_barrier();
        asm volatile("" ::: "memory");
        // ================= phase 4: stage A-h1 of kt+2; MFMA q(1,1) =======
        if (kt < NT - 2) {
            load_lds16(aS + kc + 64*KK,    aD + cb + 8192);
            load_lds16(aS + kc + 192*KK,   aD + cb + 12288);
        }
        asm volatile("" ::: "memory");
        __builtin_amdgcn_s_barrier();
        __builtin_amdgcn_s_setprio(1);
#pragma unroll
        for (int i = 0; i < 4; ++i)
#pragma unroll
            for (int f = 2; f < 4; ++f) {
                acc[4 + i][f] = mf(aR[i][0], bR[f][0], acc[4 + i][f]);
                acc[4 + i][f] = mf(aR[i][1], bR[f][1], acc[4 + i][f]);
            }
        __builtin_amdgcn_s_setprio(0);
        // counted vmcnt: 16 in flight (kt+1's 8 + kt+2's 8) -> leave 8:
        // kt+1's buffer guaranteed landed, kt+2's loads stay in flight.
        if (kt < NT - 2) { asm volatile("s_waitcnt vmcnt(8)" ::: "memory"); }
        else             { asm volatile("s_waitcnt vmcnt(0)" ::: "memory"); }
        __builtin_amdgcn_sched_barrier(0);
        __builtin_amdgcn_s_barrier();
        asm volatile("" ::: "memory");
    }

    // ---- epilogue C-write (C/D map: col=l16, row=q*4+reg) ----------------
#pragma unroll
    for (int fm = 0; fm < 8; ++fm) {
#pragma unroll
        for (int rg = 0; rg < 4; ++rg) {
            const int row = by * 256 + wm * 128 + fm * 16 + q * 4 + rg;
            u16* yp = Y + (size_t)row * NN + bx * 256 + wn * 64 + l16;
#pragma unroll
            for (int fn = 0; fn < 4; ++fn) yp[fn * 16] = f2b(acc[fm][fn][rg]);
        }
    }
}

// ---- K2: rowwise LN(2048)+sigmoid -> FN=(f,nd) packed, R -----------------
__global__ __launch_bounds__(256) void k_lnsig(const u16* __restrict__ Y,
                                               const float* __restrict__ bg,
                                               const float* __restrict__ gg,
                                               const float* __restrict__ bt,
                                               uint32_t* __restrict__ FN,
                                               u16* __restrict__ R) {
    const int row = blockIdx.x;
    const int t = threadIdx.x;
    const u16* yr = Y + (size_t)row * 3072;
    us8 gv = *(const us8*)(yr + 1024 + t * 8);
    float z[8];
    float s = 0.f, s2 = 0.f;
#pragma unroll
    for (int k = 0; k < 8; k++) {
        z[k] = b2f(gv[k]) + bg[t * 8 + k];
        s += z[k];
        s2 += z[k] * z[k];
    }
#pragma unroll
    for (int m = 1; m < 64; m <<= 1) {
        s += __shfl_xor(s, m);
        s2 += __shfl_xor(s2, m);
    }
    __shared__ float red[8];
    if ((t & 63) == 0) { red[t >> 6] = s; red[(t >> 6) + 4] = s2; }
    __syncthreads();
    s = red[0] + red[1] + red[2] + red[3];
    s2 = red[4] + red[5] + red[6] + red[7];
    const float mu = s * (1.f / 2048.f);
    const float inv = rsqrtf(s2 * (1.f / 2048.f) - mu * mu + 1e-5f);
    float gate[8];
#pragma unroll
    for (int k = 0; k < 8; k++)
        gate[k] = sigm((z[k] - mu) * inv * gg[t * 8 + k] + bt[t * 8 + k]);
    if (t < 128) {
        us8 xt = *(const us8*)(yr + t * 8);
        u32x8 fn;
#pragma unroll
        for (int k = 0; k < 8; k++) {
            u16 fb = f2b(gate[k]);
            u16 nb = f2b((1.f - gate[k]) * b2f(xt[k]));
            fn[k] = (uint32_t)fb | ((uint32_t)nb << 16);
        }
        *(u32x8*)(FN + (size_t)row * 1024 + t * 8) = fn;
    } else {
        us8 ro;
#pragma unroll
        for (int k = 0; k < 8; k++) ro[k] = f2b(gate[k]);
        *(us8*)(R + (size_t)row * 1024 + (t - 128) * 8) = ro;
    }
}

// ---- K3: scan pass 1 — per-(b,h,chunk) aggregates, 2 h per thread --------
__global__ __launch_bounds__(256) void k_scan1(const uint32_t* __restrict__ FN,
                                               float2* __restrict__ agg) {
    int u = blockIdx.x * 256 + threadIdx.x;   // 262144
    int h2 = u & 511;                          // h = 2*h2
    int chunk = (u >> 9) & 31;
    int b = u >> 14;
    size_t base = (size_t)(b * 2048 + chunk * 64) * 1024 + h2 * 2;
    float F0 = 1.f, N0 = 0.f, F1 = 1.f, N1 = 0.f;
#pragma unroll 4
    for (int i = 0; i < 64; i++) {
        uint2 v = *(const uint2*)(FN + base + (size_t)i * 1024);
        float f0 = b2f((u16)(v.x & 0xffffu)), n0 = b2f((u16)(v.x >> 16));
        float f1 = b2f((u16)(v.y & 0xffffu)), n1 = b2f((u16)(v.y >> 16));
        N0 = fmaf(f0, N0, n0); F0 *= f0;
        N1 = fmaf(f1, N1, n1); F1 *= f1;
    }
    float4 o = {F0, N0, F1, N1};
    *(float4*)&agg[(size_t)(b * 32 + chunk) * 1024 + h2 * 2] = o;
}

// ---- K4: scan over chunk aggregates -> per-chunk prefix P [b][chunk][h] --
__global__ __launch_bounds__(256) void k_scan2(const float2* __restrict__ agg,
                                               const float* __restrict__ c0,
                                               float* __restrict__ P) {
    int u = blockIdx.x * 256 + threadIdx.x;  // (b*1024+h), 16384 total
    int b = u >> 10, h = u & 1023;
    float c = c0[u];
#pragma unroll 4
    for (int k = 0; k < 32; k++) {
        size_t idx = (size_t)(b * 32 + k) * 1024 + h;
        P[idx] = c;
        float2 fn = agg[idx];
        c = fmaf(fn.x, c, fn.y);
    }
}

// ---- K5: fused scan pass 2 + LN_h + output h (no C materialization) ------
__global__ __launch_bounds__(512) void k_scanout(const uint32_t* __restrict__ FN,
                                                 const float* __restrict__ P,
                                                 const u16* __restrict__ R,
                                                 const u16* __restrict__ xb,
                                                 const float* __restrict__ ga,
                                                 const float* __restrict__ ba,
                                                 float* __restrict__ out,
                                                 float* __restrict__ cfin) {
    __shared__ float2 red[2][8];
    const int t = threadIdx.x;
    const int b = blockIdx.x >> 5, chunk = blockIdx.x & 31;
    const int h = t * 2;
    const int w = t >> 6, lane = t & 63;
    float2 cp = *(const float2*)&P[(size_t)(b * 32 + chunk) * 1024 + h];
    float c0 = cp.x, c1 = cp.y;
    const float g0 = ga[h], g1 = ga[h + 1];
    const float be0 = ba[h], be1 = ba[h + 1];
    const size_t base = (size_t)(b * 2048 + chunk * 64) * 1024 + h;
#pragma unroll 2
    for (int i = 0; i < 64; i++) {
        const size_t ro = base + (size_t)i * 1024;
        uint2 fn = *(const uint2*)(FN + ro);
        uint32_t rv = *(const uint32_t*)(R + ro);   // prefetched before reduce
        uint32_t xv = *(const uint32_t*)(xb + ro);
        c0 = fmaf(b2f((u16)(fn.x & 0xffffu)), c0, b2f((u16)(fn.x >> 16)));
        c1 = fmaf(b2f((u16)(fn.y & 0xffffu)), c1, b2f((u16)(fn.y >> 16)));
        float s = c0 + c1, s2 = c0 * c0 + c1 * c1;
#pragma unroll
        for (int m = 1; m < 64; m <<= 1) {
            s += __shfl_xor(s, m);
            s2 += __shfl_xor(s2, m);
        }
        const int p = i & 1;
        if (lane == 0) red[p][w] = make_float2(s, s2);
        __syncthreads();
        s = 0.f; s2 = 0.f;
#pragma unroll
        for (int k = 0; k < 8; k++) { float2 v = red[p][k]; s += v.x; s2 += v.y; }
        const float mu = s * (1.f / 1024.f);
        const float inv = rsqrtf(s2 * (1.f / 1024.f) - mu * mu + 1e-5f);
        const float sg0 = sigm((c0 - mu) * inv * g0 + be0);
        const float sg1 = sigm((c1 - mu) * inv * g1 + be1);
        const float r0 = b2f((u16)(rv & 0xffffu)), r1 = b2f((u16)(rv >> 16));
        const float x0 = b2f((u16)(xv & 0xffffu)), x1 = b2f((u16)(xv >> 16));
        float2 ho = {r0 * sg0 + (1.f - r0) * x0, r1 * sg1 + (1.f - r1) * x1};
        *(float2*)(out + ro) = ho;
    }
    if (chunk == 31) *(float2*)(cfin + b * 1024 + h) = make_float2(c0, c1);
}

extern "C" void kernel_launch(void* const* d_in, const int* in_sizes, int n_in,
                              void* d_out, int out_size, void* d_ws, size_t ws_size,
                              hipStream_t stream) {
    const float* x   = (const float*)d_in[0];
    const float* c0  = (const float*)d_in[1];
    const float* wlt = (const float*)d_in[2];
    const float* wg  = (const float*)d_in[3];
    const float* bg  = (const float*)d_in[4];
    const float* gg  = (const float*)d_in[5];
    const float* btg = (const float*)d_in[6];
    const float* ga  = (const float*)d_in[7];
    const float* ba  = (const float*)d_in[8];
    float* out = (float*)d_out;

    char* ws = (char*)d_ws;
    u16* xb      = (u16*)(ws);                  //  67,108,864 B
    u16* wb      = (u16*)(ws + 67108864);       //   6,291,456 B
    u16* y       = (u16*)(ws + 73400320);       // 201,326,592 B
    uint32_t* FN = (uint32_t*)(ws + 274726912); // 134,217,728 B
    u16* R       = (u16*)(ws + 408944640);      //  67,108,864 B
    float2* agg  = (float2*)(ws + 476053504);   //   4,194,304 B
    float* P     = (float*)(ws + 480247808);    //   2,097,152 B

    k_cvt<<<17920, 256, 0, stream>>>(x, wlt, wg, xb, wb);
    k_gemm<<<dim3(NN / 256, MM / 256), 512, 0, stream>>>(xb, wb, y);
    k_lnsig<<<32768, 256, 0, stream>>>(y, bg, gg, btg, FN, R);
    k_scan1<<<1024, 256, 0, stream>>>(FN, agg);
    k_scan2<<<64, 256, 0, stream>>>(agg, c0, P);
    k_scanout<<<512, 512, 0, stream>>>(FN, P, R, xb, ga, ba, out,
                                       out + (size_t)33554432);
}

// Round 2
// 663.604 us; speedup vs baseline: 1.0311x; 1.0084x over previous
//
#include <hip/hip_runtime.h>
#include <stdint.h>

typedef unsigned short u16;
typedef u16 us8 __attribute__((ext_vector_type(8)));
typedef uint32_t u32x8 __attribute__((ext_vector_type(8)));
typedef __bf16 bf16x8 __attribute__((ext_vector_type(8)));
typedef float f32x4 __attribute__((ext_vector_type(4)));

#define BB 16
#define TT 2048
#define HH 1024
#define MM 32768   // B*T
#define NN 3072    // H + 2H
#define KK 1024
#define NT 16      // K-tiles of 64

__device__ __forceinline__ float b2f(u16 u) {
    union { uint32_t i; float f; } v; v.i = ((uint32_t)u) << 16; return v.f;
}
__device__ __forceinline__ u16 f2b(float f) {
    union { uint32_t i; float f; } v; v.f = f;
    uint32_t r = v.i + 0x7fffu + ((v.i >> 16) & 1u);
    return (u16)(r >> 16);
}
__device__ __forceinline__ float sigm(float z) {
    return 1.f / (1.f + __expf(-z));
}
__device__ __forceinline__ void load_lds16(const u16* g, u16* l) {
    __builtin_amdgcn_global_load_lds(
        (const __attribute__((address_space(1))) void*)g,
        (__attribute__((address_space(3))) void*)l, 16, 0, 0);
}
__device__ __forceinline__ f32x4 mf(bf16x8 a, bf16x8 b, f32x4 c) {
    return __builtin_amdgcn_mfma_f32_16x16x32_bf16(a, b, c, 0, 0, 0);
}
#define MEMBAR() asm volatile("" ::: "memory")

// ---- K0: x fp32 -> bf16, [W_lt;W_g] fp32 -> bf16 (merged) ----------------
__global__ __launch_bounds__(256) void k_cvt(const float* __restrict__ x,
                                             const float* __restrict__ wlt,
                                             const float* __restrict__ wg,
                                             u16* __restrict__ xb,
                                             u16* __restrict__ wb) {
    long i = (long)(blockIdx.x * 256 + threadIdx.x) * 8;
    const float* s;
    u16* o;
    if (i < 33554432L) { s = x + i; o = xb + i; }
    else {
        long j = i - 33554432L;
        s = (j < 1048576L) ? (wlt + j) : (wg + (j - 1048576L));
        o = wb + j;
    }
    float4 a = *(const float4*)(s);
    float4 b = *(const float4*)(s + 4);
    us8 r;
    r[0] = f2b(a.x); r[1] = f2b(a.y); r[2] = f2b(a.z); r[3] = f2b(a.w);
    r[4] = f2b(b.x); r[5] = f2b(b.y); r[6] = f2b(b.z); r[7] = f2b(b.w);
    *(us8*)o = r;
}

// ---- K1: Y[32768,3072] = Xb @ Wb^T  (256x256, 4 k-slot phases, read-ahead)
// 512 thr = 8 waves (2M x 4N); BK=64; LDS 128 KiB dbuf.
// Pipelined operand fetch: each phase issues the NEXT phase's ds_reads
// before its own MFMA cluster; compiler emits counted lgkmcnt so the LDS
// pipe overlaps the MFMA pipe. B fragments are register-resident for two
// phases (b0: ph1+ph3, b1: ph2+ph4). Staging order/regions identical to
// the verified round-1 kernel (A0+B regions staged in ph2, A1 in ph4,
// counted vmcnt(8), publish barrier moved before ph4's next-tile reads).
__global__ __launch_bounds__(512, 2) void k_gemm(const u16* __restrict__ A,
                                                 const u16* __restrict__ W,
                                                 u16* __restrict__ Y) {
    __shared__ u16 As[2 * 16384];
    __shared__ u16 Bs[2 * 16384];
    const int tid = threadIdx.x;
    const int lane = tid & 63;
    const int w = tid >> 6;        // 0..7
    const int wm = w >> 2;         // 0..1
    const int wn = w & 3;          // 0..3
    const int q = lane >> 4;
    const int l16 = lane & 15;
    const int bx = blockIdx.x;     // N tile (12)
    const int by = blockIdx.y;     // M tile (128)

    // staging: per-thread pre-swizzled global source, linear LDS dest.
    const int slog = ((tid & 7) ^ ((tid >> 3) & 7)) << 3;
    const u16* aS = A + (size_t)(by * 256 + (tid >> 3)) * KK + slog;
    const u16* bS = W + (size_t)(bx * 256 + ((tid >> 8) << 6) + ((tid >> 3) & 31)) * KK + slog;
    u16* aD = As + w * 512;
    u16* bD = Bs + w * 512;

    // prologue: stage kt0 -> buf0, kt1 -> buf1
    load_lds16(aS,                aD);
    load_lds16(aS + 128 * KK,     aD + 4096);
    load_lds16(aS + 64 * KK,      aD + 8192);
    load_lds16(aS + 192 * KK,     aD + 12288);
    load_lds16(bS,                bD);
    load_lds16(bS + 128 * KK,     bD + 4096);
    load_lds16(bS + 32 * KK,      bD + 8192);
    load_lds16(bS + 160 * KK,     bD + 12288);
    load_lds16(aS + 64,           aD + 16384);
    load_lds16(aS + 64 + 128*KK,  aD + 16384 + 4096);
    load_lds16(aS + 64 + 64*KK,   aD + 16384 + 8192);
    load_lds16(aS + 64 + 192*KK,  aD + 16384 + 12288);
    load_lds16(bS + 64,           bD + 16384);
    load_lds16(bS + 64 + 128*KK,  bD + 16384 + 4096);
    load_lds16(bS + 64 + 32*KK,   bD + 16384 + 8192);
    load_lds16(bS + 64 + 160*KK,  bD + 16384 + 12288);

    // ds_read lane bases (swizzled): slot(ks) = ((ks<<2)|q) ^ (l16&7)
    const int key = l16 & 7;
    const int sA0 = ((q ^ key) << 3);
    const int sA1 = (((q ^ key) ^ 4) << 3);
    const int aB0 = wm * 4096 + l16 * 64 + sA0;   // ks0
    const int aB1 = wm * 4096 + l16 * 64 + sA1;   // ks1
    const int bB0 = wn * 2048 + l16 * 64 + sA0;
    const int bB1 = wn * 2048 + l16 * 64 + sA1;

    f32x4 zero = {0.f, 0.f, 0.f, 0.f};
    f32x4 acc[8][4];
#pragma unroll
    for (int i = 0; i < 8; ++i)
#pragma unroll
        for (int j = 0; j < 4; ++j) acc[i][j] = zero;
    bf16x8 aX[4], aY[4], b0[4], b1[4];

    asm volatile("s_waitcnt vmcnt(8)" ::: "memory");   // kt0 landed; kt1 in flight
    __builtin_amdgcn_sched_barrier(0);
    __builtin_amdgcn_s_barrier();
    MEMBAR();

    // initial fill: aX = A0ks0(kt0), b0 = Bks0(kt0)
#pragma unroll
    for (int i = 0; i < 4; ++i) aX[i] = *(const bf16x8*)&As[i * 1024 + aB0];
#pragma unroll
    for (int f = 0; f < 4; ++f)
        b0[f] = *(const bf16x8*)&Bs[(f >> 1) * 8192 + (f & 1) * 1024 + bB0];

    for (int kt = 0; kt < NT - 1; ++kt) {
        const int cb = (kt & 1) << 14;
        const int nb = cb ^ 16384;
        const int kc = (kt + 2) << 6;
        // ===== ph1: fill(aY=A0ks1, b1=Bks1); MFMA aX x b0 -> acc[0..3] ====
#pragma unroll
        for (int i = 0; i < 4; ++i) aY[i] = *(const bf16x8*)&As[cb + i * 1024 + aB1];
#pragma unroll
        for (int f = 0; f < 4; ++f)
            b1[f] = *(const bf16x8*)&Bs[cb + (f >> 1) * 8192 + (f & 1) * 1024 + bB1];
        __builtin_amdgcn_sched_barrier(0);
        __builtin_amdgcn_s_setprio(1);
#pragma unroll
        for (int i = 0; i < 4; ++i)
#pragma unroll
            for (int f = 0; f < 4; ++f) acc[i][f] = mf(aX[i], b0[f], acc[i][f]);
        __builtin_amdgcn_s_setprio(0);
        MEMBAR();
        __builtin_amdgcn_s_barrier();   // A0+B regions of cb fully read
        MEMBAR();
        // ===== ph2: stage A0+B of kt+2; fill(aX=A1ks0); MFMA aY x b1 ======
        if (kt < NT - 2) {
            load_lds16(aS + kc,            aD + cb);
            load_lds16(aS + kc + 128*KK,   aD + cb + 4096);
            load_lds16(bS + kc,            bD + cb);
            load_lds16(bS + kc + 128*KK,   bD + cb + 4096);
            load_lds16(bS + kc + 32*KK,    bD + cb + 8192);
            load_lds16(bS + kc + 160*KK,   bD + cb + 12288);
        }
#pragma unroll
        for (int i = 0; i < 4; ++i)
            aX[i] = *(const bf16x8*)&As[cb + 8192 + i * 1024 + aB0];
        __builtin_amdgcn_sched_barrier(0);
        __builtin_amdgcn_s_setprio(1);
#pragma unroll
        for (int i = 0; i < 4; ++i)
#pragma unroll
            for (int f = 0; f < 4; ++f) acc[i][f] = mf(aY[i], b1[f], acc[i][f]);
        __builtin_amdgcn_s_setprio(0);
        // ===== ph3: fill(aY=A1ks1); MFMA aX x b0 -> acc[4..7] =============
#pragma unroll
        for (int i = 0; i < 4; ++i)
            aY[i] = *(const bf16x8*)&As[cb + 8192 + i * 1024 + aB1];
        __builtin_amdgcn_sched_barrier(0);
        __builtin_amdgcn_s_setprio(1);
#pragma unroll
        for (int i = 0; i < 4; ++i)
#pragma unroll
            for (int f = 0; f < 4; ++f) acc[4 + i][f] = mf(aX[i], b0[f], acc[4 + i][f]);
        __builtin_amdgcn_s_setprio(0);
        MEMBAR();
        __builtin_amdgcn_s_barrier();   // A1 region of cb fully read
        MEMBAR();
        // ===== ph4: stage A1 of kt+2; vmcnt; publish kt+1; prefetch next ==
        if (kt < NT - 2) {
            load_lds16(aS + kc + 64*KK,    aD + cb + 8192);
            load_lds16(aS + kc + 192*KK,   aD + cb + 12288);
            asm volatile("s_waitcnt vmcnt(8)" ::: "memory");  // kt+1 landed
        } else {
            asm volatile("s_waitcnt vmcnt(0)" ::: "memory");  // kt+1 (=15) landed
        }
        __builtin_amdgcn_sched_barrier(0);
        __builtin_amdgcn_s_barrier();   // publish buf(kt+1)
        MEMBAR();
#pragma unroll
        for (int i = 0; i < 4; ++i) aX[i] = *(const bf16x8*)&As[nb + i * 1024 + aB0];
#pragma unroll
        for (int f = 0; f < 4; ++f)
            b0[f] = *(const bf16x8*)&Bs[nb + (f >> 1) * 8192 + (f & 1) * 1024 + bB0];
        __builtin_amdgcn_sched_barrier(0);
        __builtin_amdgcn_s_setprio(1);
#pragma unroll
        for (int i = 0; i < 4; ++i)
#pragma unroll
            for (int f = 0; f < 4; ++f) acc[4 + i][f] = mf(aY[i], b1[f], acc[4 + i][f]);
        __builtin_amdgcn_s_setprio(0);
        MEMBAR();
        __builtin_amdgcn_s_barrier();
        MEMBAR();
    }

    // ===== peeled tile 15 (buf1, no staging, no barriers needed) ==========
    {
        const int cb = 16384;
#pragma unroll
        for (int i = 0; i < 4; ++i) aY[i] = *(const bf16x8*)&As[cb + i * 1024 + aB1];
#pragma unroll
        for (int f = 0; f < 4; ++f)
            b1[f] = *(const bf16x8*)&Bs[cb + (f >> 1) * 8192 + (f & 1) * 1024 + bB1];
        __builtin_amdgcn_sched_barrier(0);
#pragma unroll
        for (int i = 0; i < 4; ++i)
#pragma unroll
            for (int f = 0; f < 4; ++f) acc[i][f] = mf(aX[i], b0[f], acc[i][f]);
#pragma unroll
        for (int i = 0; i < 4; ++i)
            aX[i] = *(const bf16x8*)&As[cb + 8192 + i * 1024 + aB0];
        __builtin_amdgcn_sched_barrier(0);
#pragma unroll
        for (int i = 0; i < 4; ++i)
#pragma unroll
            for (int f = 0; f < 4; ++f) acc[i][f] = mf(aY[i], b1[f], acc[i][f]);
#pragma unroll
        for (int i = 0; i < 4; ++i)
            aY[i] = *(const bf16x8*)&As[cb + 8192 + i * 1024 + aB1];
        __builtin_amdgcn_sched_barrier(0);
#pragma unroll
        for (int i = 0; i < 4; ++i)
#pragma unroll
            for (int f = 0; f < 4; ++f) acc[4 + i][f] = mf(aX[i], b0[f], acc[4 + i][f]);
        __builtin_amdgcn_sched_barrier(0);
#pragma unroll
        for (int i = 0; i < 4; ++i)
#pragma unroll
            for (int f = 0; f < 4; ++f) acc[4 + i][f] = mf(aY[i], b1[f], acc[4 + i][f]);
    }

    // ---- epilogue C-write (C/D map: col=l16, row=q*4+reg) ----------------
#pragma unroll
    for (int fm = 0; fm < 8; ++fm) {
#pragma unroll
        for (int rg = 0; rg < 4; ++rg) {
            const int row = by * 256 + wm * 128 + fm * 16 + q * 4 + rg;
            u16* yp = Y + (size_t)row * NN + bx * 256 + wn * 64 + l16;
#pragma unroll
            for (int fn = 0; fn < 4; ++fn) yp[fn * 16] = f2b(acc[fm][fn][rg]);
        }
    }
}

// ---- K2: rowwise LN(2048)+sigmoid -> FN=(f,nd) packed, R -----------------
__global__ __launch_bounds__(256) void k_lnsig(const u16* __restrict__ Y,
                                               const float* __restrict__ bg,
                                               const float* __restrict__ gg,
                                               const float* __restrict__ bt,
                                               uint32_t* __restrict__ FN,
                                               u16* __restrict__ R) {
    const int row = blockIdx.x;
    const int t = threadIdx.x;
    const u16* yr = Y + (size_t)row * 3072;
    us8 gv = *(const us8*)(yr + 1024 + t * 8);
    float z[8];
    float s = 0.f, s2 = 0.f;
#pragma unroll
    for (int k = 0; k < 8; k++) {
        z[k] = b2f(gv[k]) + bg[t * 8 + k];
        s += z[k];
        s2 += z[k] * z[k];
    }
#pragma unroll
    for (int m = 1; m < 64; m <<= 1) {
        s += __shfl_xor(s, m);
        s2 += __shfl_xor(s2, m);
    }
    __shared__ float red[8];
    if ((t & 63) == 0) { red[t >> 6] = s; red[(t >> 6) + 4] = s2; }
    __syncthreads();
    s = red[0] + red[1] + red[2] + red[3];
    s2 = red[4] + red[5] + red[6] + red[7];
    const float mu = s * (1.f / 2048.f);
    const float inv = rsqrtf(s2 * (1.f / 2048.f) - mu * mu + 1e-5f);
    float gate[8];
#pragma unroll
    for (int k = 0; k < 8; k++)
        gate[k] = sigm((z[k] - mu) * inv * gg[t * 8 + k] + bt[t * 8 + k]);
    if (t < 128) {
        us8 xt = *(const us8*)(yr + t * 8);
        u32x8 fn;
#pragma unroll
        for (int k = 0; k < 8; k++) {
            u16 fb = f2b(gate[k]);
            u16 nb = f2b((1.f - gate[k]) * b2f(xt[k]));
            fn[k] = (uint32_t)fb | ((uint32_t)nb << 16);
        }
        *(u32x8*)(FN + (size_t)row * 1024 + t * 8) = fn;
    } else {
        us8 ro;
#pragma unroll
        for (int k = 0; k < 8; k++) ro[k] = f2b(gate[k]);
        *(us8*)(R + (size_t)row * 1024 + (t - 128) * 8) = ro;
    }
}

// ---- K3: scan pass 1 — per-(b,h,chunk) aggregates, 2 h per thread --------
__global__ __launch_bounds__(256) void k_scan1(const uint32_t* __restrict__ FN,
                                               float2* __restrict__ agg) {
    int u = blockIdx.x * 256 + threadIdx.x;   // 262144
    int h2 = u & 511;                          // h = 2*h2
    int chunk = (u >> 9) & 31;
    int b = u >> 14;
    size_t base = (size_t)(b * 2048 + chunk * 64) * 1024 + h2 * 2;
    float F0 = 1.f, N0 = 0.f, F1 = 1.f, N1 = 0.f;
#pragma unroll 4
    for (int i = 0; i < 64; i++) {
        uint2 v = *(const uint2*)(FN + base + (size_t)i * 1024);
        float f0 = b2f((u16)(v.x & 0xffffu)), n0 = b2f((u16)(v.x >> 16));
        float f1 = b2f((u16)(v.y & 0xffffu)), n1 = b2f((u16)(v.y >> 16));
        N0 = fmaf(f0, N0, n0); F0 *= f0;
        N1 = fmaf(f1, N1, n1); F1 *= f1;
    }
    float4 o = {F0, N0, F1, N1};
    *(float4*)&agg[(size_t)(b * 32 + chunk) * 1024 + h2 * 2] = o;
}

// ---- K4: scan over chunk aggregates -> per-chunk prefix P [b][chunk][h] --
__global__ __launch_bounds__(256) void k_scan2(const float2* __restrict__ agg,
                                               const float* __restrict__ c0,
                                               float* __restrict__ P) {
    int u = blockIdx.x * 256 + threadIdx.x;  // (b*1024+h), 16384 total
    int b = u >> 10, h = u & 1023;
    float c = c0[u];
#pragma unroll 4
    for (int k = 0; k < 32; k++) {
        size_t idx = (size_t)(b * 32 + k) * 1024 + h;
        P[idx] = c;
        float2 fn = agg[idx];
        c = fmaf(fn.x, c, fn.y);
    }
}

// ---- K5: fused scan pass 2 + LN_h + output h (no C materialization) ------
__global__ __launch_bounds__(512) void k_scanout(const uint32_t* __restrict__ FN,
                                                 const float* __restrict__ P,
                                                 const u16* __restrict__ R,
                                                 const u16* __restrict__ xb,
                                                 const float* __restrict__ ga,
                                                 const float* __restrict__ ba,
                                                 float* __restrict__ out,
                                                 float* __restrict__ cfin) {
    __shared__ float2 red[2][8];
    const int t = threadIdx.x;
    const int b = blockIdx.x >> 5, chunk = blockIdx.x & 31;
    const int h = t * 2;
    const int w = t >> 6, lane = t & 63;
    float2 cp = *(const float2*)&P[(size_t)(b * 32 + chunk) * 1024 + h];
    float c0 = cp.x, c1 = cp.y;
    const float g0 = ga[h], g1 = ga[h + 1];
    const float be0 = ba[h], be1 = ba[h + 1];
    const size_t base = (size_t)(b * 2048 + chunk * 64) * 1024 + h;
#pragma unroll 2
    for (int i = 0; i < 64; i++) {
        const size_t ro = base + (size_t)i * 1024;
        uint2 fn = *(const uint2*)(FN + ro);
        uint32_t rv = *(const uint32_t*)(R + ro);   // prefetched before reduce
        uint32_t xv = *(const uint32_t*)(xb + ro);
        c0 = fmaf(b2f((u16)(fn.x & 0xffffu)), c0, b2f((u16)(fn.x >> 16)));
        c1 = fmaf(b2f((u16)(fn.y & 0xffffu)), c1, b2f((u16)(fn.y >> 16)));
        float s = c0 + c1, s2 = c0 * c0 + c1 * c1;
#pragma unroll
        for (int m = 1; m < 64; m <<= 1) {
            s += __shfl_xor(s, m);
            s2 += __shfl_xor(s2, m);
        }
        const int p = i & 1;
        if (lane == 0) red[p][w] = make_float2(s, s2);
        __syncthreads();
        s = 0.f; s2 = 0.f;
#pragma unroll
        for (int k = 0; k < 8; k++) { float2 v = red[p][k]; s += v.x; s2 += v.y; }
        const float mu = s * (1.f / 1024.f);
        const float inv = rsqrtf(s2 * (1.f / 1024.f) - mu * mu + 1e-5f);
        const float sg0 = sigm((c0 - mu) * inv * g0 + be0);
        const float sg1 = sigm((c1 - mu) * inv * g1 + be1);
        const float r0 = b2f((u16)(rv & 0xffffu)), r1 = b2f((u16)(rv >> 16));
        const float x0 = b2f((u16)(xv & 0xffffu)), x1 = b2f((u16)(xv >> 16));
        float2 ho = {r0 * sg0 + (1.f - r0) * x0, r1 * sg1 + (1.f - r1) * x1};
        *(float2*)(out + ro) = ho;
    }
    if (chunk == 31) *(float2*)(cfin + b * 1024 + h) = make_float2(c0, c1);
}

extern "C" void kernel_launch(void* const* d_in, const int* in_sizes, int n_in,
                              void* d_out, int out_size, void* d_ws, size_t ws_size,
                              hipStream_t stream) {
    const float* x   = (const float*)d_in[0];
    const float* c0  = (const float*)d_in[1];
    const float* wlt = (const float*)d_in[2];
    const float* wg  = (const float*)d_in[3];
    const float* bg  = (const float*)d_in[4];
    const float* gg  = (const float*)d_in[5];
    const float* btg = (const float*)d_in[6];
    const float* ga  = (const float*)d_in[7];
    const float* ba  = (const float*)d_in[8];
    float* out = (float*)d_out;

    char* ws = (char*)d_ws;
    u16* xb      = (u16*)(ws);                  //  67,108,864 B
    u16* wb      = (u16*)(ws + 67108864);       //   6,291,456 B
    u16* y       = (u16*)(ws + 73400320);       // 201,326,592 B
    uint32_t* FN = (uint32_t*)(ws + 274726912); // 134,217,728 B
    u16* R       = (u16*)(ws + 408944640);      //  67,108,864 B
    float2* agg  = (float2*)(ws + 476053504);   //   4,194,304 B
    float* P     = (float*)(ws + 480247808);    //   2,097,152 B

    k_cvt<<<17920, 256, 0, stream>>>(x, wlt, wg, xb, wb);
    k_gemm<<<dim3(NN / 256, MM / 256), 512, 0, stream>>>(xb, wb, y);
    k_lnsig<<<32768, 256, 0, stream>>>(y, bg, gg, btg, FN, R);
    k_scan1<<<1024, 256, 0, stream>>>(FN, agg);
    k_scan2<<<64, 256, 0, stream>>>(agg, c0, P);
    k_scanout<<<512, 512, 0, stream>>>(FN, P, R, xb, ga, ba, out,
                                       out + (size_t)33554432);
}

// Round 3
// 632.346 us; speedup vs baseline: 1.0820x; 1.0494x over previous
//
#include <hip/hip_runtime.h>
#include <stdint.h>

typedef unsigned short u16;
typedef u16 us8 __attribute__((ext_vector_type(8)));
typedef uint32_t u32x8 __attribute__((ext_vector_type(8)));
typedef __bf16 bf16x8 __attribute__((ext_vector_type(8)));
typedef float f32x4 __attribute__((ext_vector_type(4)));

#define BB 16
#define TT 2048
#define HH 1024
#define MM 32768   // B*T
#define NN 3072    // H + 2H
#define KK 1024
#define NT 16      // K-tiles of 64

__device__ __forceinline__ float b2f(u16 u) {
    union { uint32_t i; float f; } v; v.i = ((uint32_t)u) << 16; return v.f;
}
__device__ __forceinline__ u16 f2b(float f) {
    union { uint32_t i; float f; } v; v.f = f;
    uint32_t r = v.i + 0x7fffu + ((v.i >> 16) & 1u);
    return (u16)(r >> 16);
}
__device__ __forceinline__ float sigm(float z) {
    return 1.f / (1.f + __expf(-z));
}
__device__ __forceinline__ void load_lds16(const u16* g, u16* l) {
    __builtin_amdgcn_global_load_lds(
        (const __attribute__((address_space(1))) void*)g,
        (__attribute__((address_space(3))) void*)l, 16, 0, 0);
}
__device__ __forceinline__ f32x4 mf(bf16x8 a, bf16x8 b, f32x4 c) {
    return __builtin_amdgcn_mfma_f32_16x16x32_bf16(a, b, c, 0, 0, 0);
}
#define MEMBAR() asm volatile("" ::: "memory")

// ---- K0: x fp32 -> bf16, [W_lt;W_g] fp32 -> bf16 (merged) ----------------
__global__ __launch_bounds__(256) void k_cvt(const float* __restrict__ x,
                                             const float* __restrict__ wlt,
                                             const float* __restrict__ wg,
                                             u16* __restrict__ xb,
                                             u16* __restrict__ wb) {
    long i = (long)(blockIdx.x * 256 + threadIdx.x) * 8;
    const float* s;
    u16* o;
    if (i < 33554432L) { s = x + i; o = xb + i; }
    else {
        long j = i - 33554432L;
        s = (j < 1048576L) ? (wlt + j) : (wg + (j - 1048576L));
        o = wb + j;
    }
    float4 a = *(const float4*)(s);
    float4 b = *(const float4*)(s + 4);
    us8 r;
    r[0] = f2b(a.x); r[1] = f2b(a.y); r[2] = f2b(a.z); r[3] = f2b(a.w);
    r[4] = f2b(b.x); r[5] = f2b(b.y); r[6] = f2b(b.z); r[7] = f2b(b.w);
    *(us8*)o = r;
}

// ---- K1: Y[32768,3072] = Xb @ Wb^T  (m201-faithful 4-phase, XCD swizzle) -
// 512 thr = 8 waves (2M x 4N); BK=64; LDS 128 KiB dbuf; per-wave C 128x64.
// Per phase: {ds-reads, stage (released regions only), [lgkmcnt(8)],
// s_barrier, lgkmcnt(0)+sched_barrier, setprio(1), 16 MFMA, setprio(0),
// s_barrier}. Race-free: phase-p reads complete (lgkmcnt0) before p's MFMA,
// which precedes the barrier that releases those regions for staging in p+1.
// vmcnt(8) once per K-tile at ph4 (tile j+1 landed; j+2's 8 stay in flight).
__global__ __launch_bounds__(512, 2) void k_gemm(const u16* __restrict__ A,
                                                 const u16* __restrict__ W,
                                                 u16* __restrict__ Y) {
    __shared__ u16 As[2 * 16384];
    __shared__ u16 Bs[2 * 16384];
    const int tid = threadIdx.x;
    const int lane = tid & 63;
    const int w = tid >> 6;        // 0..7
    const int wm = w >> 2;         // 0..1
    const int wn = w & 3;          // 0..3
    const int q = lane >> 4;
    const int l16 = lane & 15;

    // XCD-aware bijective swizzle: nwg=1536, 192 per XCD; consecutive sw on
    // one XCD share the A row-panel (by) -> L2 reuse.
    const unsigned bid = blockIdx.y * 12u + blockIdx.x;
    const unsigned sw = (bid & 7u) * 192u + (bid >> 3);
    const int by = sw / 12u;       // 0..127
    const int bx = sw % 12u;       // 0..11

    // staging: per-thread pre-swizzled global source, linear LDS dest.
    const int slog = ((tid & 7) ^ ((tid >> 3) & 7)) << 3;
    const u16* aS = A + (size_t)(by * 256 + (tid >> 3)) * KK + slog;
    const u16* bS = W + (size_t)(bx * 256 + ((tid >> 8) << 6) + ((tid >> 3) & 31)) * KK + slog;
    u16* aD = As + w * 512;
    u16* bD = Bs + w * 512;

    // prologue: stage kt0 -> buf0, kt1 -> buf1
    load_lds16(aS,                aD);
    load_lds16(aS + 128 * KK,     aD + 4096);
    load_lds16(aS + 64 * KK,      aD + 8192);
    load_lds16(aS + 192 * KK,     aD + 12288);
    load_lds16(bS,                bD);
    load_lds16(bS + 128 * KK,     bD + 4096);
    load_lds16(bS + 32 * KK,      bD + 8192);
    load_lds16(bS + 160 * KK,     bD + 12288);
    load_lds16(aS + 64,           aD + 16384);
    load_lds16(aS + 64 + 128*KK,  aD + 16384 + 4096);
    load_lds16(aS + 64 + 64*KK,   aD + 16384 + 8192);
    load_lds16(aS + 64 + 192*KK,  aD + 16384 + 12288);
    load_lds16(bS + 64,           bD + 16384);
    load_lds16(bS + 64 + 128*KK,  bD + 16384 + 4096);
    load_lds16(bS + 64 + 32*KK,   bD + 16384 + 8192);
    load_lds16(bS + 64 + 160*KK,  bD + 16384 + 12288);

    // ds_read lane bases (swizzled): slot(ks) = ((ks<<2)|q) ^ (l16&7)
    const int key = l16 & 7;
    const int sA0 = ((q ^ key) << 3);
    const int sA1 = (((q ^ key) ^ 4) << 3);
    const int aB0 = wm * 4096 + l16 * 64 + sA0;   // ks0
    const int aB1 = wm * 4096 + l16 * 64 + sA1;   // ks1
    const int bB0 = wn * 2048 + l16 * 64 + sA0;
    const int bB1 = wn * 2048 + l16 * 64 + sA1;

    f32x4 zero = {0.f, 0.f, 0.f, 0.f};
    f32x4 acc[8][4];
#pragma unroll
    for (int i = 0; i < 8; ++i)
#pragma unroll
        for (int j = 0; j < 4; ++j) acc[i][j] = zero;
    bf16x8 aX[4], aY[4], bLo[4], bHi[4];

    asm volatile("s_waitcnt vmcnt(8)" ::: "memory");   // kt0 landed; kt1 in flight
    __builtin_amdgcn_sched_barrier(0);
    __builtin_amdgcn_s_barrier();
    MEMBAR();

    for (int kt = 0; kt < NT - 1; ++kt) {
        const int cb = (kt & 1) << 14;
        const int kc = (kt + 2) << 6;
        const bool st = (kt < NT - 2);
        // ===== ph1 (mh0 x nh0): reads A0(8) + B-lo(4); no stage ===========
#pragma unroll
        for (int i = 0; i < 4; ++i) {
            aX[i] = *(const bf16x8*)&As[cb + i * 1024 + aB0];
            aY[i] = *(const bf16x8*)&As[cb + i * 1024 + aB1];
        }
        bLo[0] = *(const bf16x8*)&Bs[cb + bB0];
        bLo[1] = *(const bf16x8*)&Bs[cb + bB1];
        bLo[2] = *(const bf16x8*)&Bs[cb + 1024 + bB0];
        bLo[3] = *(const bf16x8*)&Bs[cb + 1024 + bB1];
        asm volatile("s_waitcnt lgkmcnt(8)" ::: "memory");
        __builtin_amdgcn_sched_barrier(0);
        __builtin_amdgcn_s_barrier();
        asm volatile("s_waitcnt lgkmcnt(0)" ::: "memory");
        __builtin_amdgcn_sched_barrier(0);
        __builtin_amdgcn_s_setprio(1);
#pragma unroll
        for (int i = 0; i < 4; ++i) {
            acc[i][0] = mf(aX[i], bLo[0], acc[i][0]);
            acc[i][0] = mf(aY[i], bLo[1], acc[i][0]);
            acc[i][1] = mf(aX[i], bLo[2], acc[i][1]);
            acc[i][1] = mf(aY[i], bLo[3], acc[i][1]);
        }
        __builtin_amdgcn_s_setprio(0);
        MEMBAR();
        __builtin_amdgcn_s_barrier();   // releases A0 + B-lo regions of cb
        MEMBAR();
        // ===== ph2 (mh0 x nh1): reads B-hi(4); stage A0+Blo of kt+2 (4) ===
        bHi[0] = *(const bf16x8*)&Bs[cb + 8192 + bB0];
        bHi[1] = *(const bf16x8*)&Bs[cb + 8192 + bB1];
        bHi[2] = *(const bf16x8*)&Bs[cb + 8192 + 1024 + bB0];
        bHi[3] = *(const bf16x8*)&Bs[cb + 8192 + 1024 + bB1];
        if (st) {
            load_lds16(aS + kc,            aD + cb);
            load_lds16(aS + kc + 128*KK,   aD + cb + 4096);
            load_lds16(bS + kc,            bD + cb);
            load_lds16(bS + kc + 128*KK,   bD + cb + 4096);
        }
        __builtin_amdgcn_sched_barrier(0);
        __builtin_amdgcn_s_barrier();
        asm volatile("s_waitcnt lgkmcnt(0)" ::: "memory");
        __builtin_amdgcn_sched_barrier(0);
        __builtin_amdgcn_s_setprio(1);
#pragma unroll
        for (int i = 0; i < 4; ++i) {
            acc[i][2] = mf(aX[i], bHi[0], acc[i][2]);
            acc[i][2] = mf(aY[i], bHi[1], acc[i][2]);
            acc[i][3] = mf(aX[i], bHi[2], acc[i][3]);
            acc[i][3] = mf(aY[i], bHi[3], acc[i][3]);
        }
        __builtin_amdgcn_s_setprio(0);
        MEMBAR();
        __builtin_amdgcn_s_barrier();   // releases B-hi region of cb
        MEMBAR();
        // ===== ph3 (mh1 x nh0): reads A1(8); stage B-hi of kt+2 (2) =======
#pragma unroll
        for (int i = 0; i < 4; ++i) {
            aX[i] = *(const bf16x8*)&As[cb + 8192 + i * 1024 + aB0];
            aY[i] = *(const bf16x8*)&As[cb + 8192 + i * 1024 + aB1];
        }
        if (st) {
            load_lds16(bS + kc + 32*KK,    bD + cb + 8192);
            load_lds16(bS + kc + 160*KK,   bD + cb + 12288);
        }
        __builtin_amdgcn_sched_barrier(0);
        __builtin_amdgcn_s_barrier();
        asm volatile("s_waitcnt lgkmcnt(0)" ::: "memory");
        __builtin_amdgcn_sched_barrier(0);
        __builtin_amdgcn_s_setprio(1);
#pragma unroll
        for (int i = 0; i < 4; ++i) {
            acc[4 + i][0] = mf(aX[i], bLo[0], acc[4 + i][0]);
            acc[4 + i][0] = mf(aY[i], bLo[1], acc[4 + i][0]);
            acc[4 + i][1] = mf(aX[i], bLo[2], acc[4 + i][1]);
            acc[4 + i][1] = mf(aY[i], bLo[3], acc[4 + i][1]);
        }
        __builtin_amdgcn_s_setprio(0);
        MEMBAR();
        __builtin_amdgcn_s_barrier();   // releases A1 region of cb
        MEMBAR();
        // ===== ph4 (mh1 x nh1): no reads; stage A1 of kt+2 (2); vmcnt =====
        if (st) {
            load_lds16(aS + kc + 64*KK,    aD + cb + 8192);
            load_lds16(aS + kc + 192*KK,   aD + cb + 12288);
        }
        __builtin_amdgcn_sched_barrier(0);
        __builtin_amdgcn_s_barrier();
        __builtin_amdgcn_s_setprio(1);
#pragma unroll
        for (int i = 0; i < 4; ++i) {
            acc[4 + i][2] = mf(aX[i], bHi[0], acc[4 + i][2]);
            acc[4 + i][2] = mf(aY[i], bHi[1], acc[4 + i][2]);
            acc[4 + i][3] = mf(aX[i], bHi[2], acc[4 + i][3]);
            acc[4 + i][3] = mf(aY[i], bHi[3], acc[4 + i][3]);
        }
        __builtin_amdgcn_s_setprio(0);
        if (st) { asm volatile("s_waitcnt vmcnt(8)" ::: "memory"); }
        else    { asm volatile("s_waitcnt vmcnt(0)" ::: "memory"); }
        __builtin_amdgcn_sched_barrier(0);
        __builtin_amdgcn_s_barrier();   // publish buf(kt+1)
        MEMBAR();
    }

    // ===== peeled tile 15 (buf1; no staging, no barriers needed) ==========
    {
        const int cb = 16384;
#pragma unroll
        for (int i = 0; i < 4; ++i) {
            aX[i] = *(const bf16x8*)&As[cb + i * 1024 + aB0];
            aY[i] = *(const bf16x8*)&As[cb + i * 1024 + aB1];
        }
        bLo[0] = *(const bf16x8*)&Bs[cb + bB0];
        bLo[1] = *(const bf16x8*)&Bs[cb + bB1];
        bLo[2] = *(const bf16x8*)&Bs[cb + 1024 + bB0];
        bLo[3] = *(const bf16x8*)&Bs[cb + 1024 + bB1];
        bHi[0] = *(const bf16x8*)&Bs[cb + 8192 + bB0];
        bHi[1] = *(const bf16x8*)&Bs[cb + 8192 + bB1];
        bHi[2] = *(const bf16x8*)&Bs[cb + 8192 + 1024 + bB0];
        bHi[3] = *(const bf16x8*)&Bs[cb + 8192 + 1024 + bB1];
#pragma unroll
        for (int i = 0; i < 4; ++i) {
            acc[i][0] = mf(aX[i], bLo[0], acc[i][0]);
            acc[i][0] = mf(aY[i], bLo[1], acc[i][0]);
            acc[i][1] = mf(aX[i], bLo[2], acc[i][1]);
            acc[i][1] = mf(aY[i], bLo[3], acc[i][1]);
            acc[i][2] = mf(aX[i], bHi[0], acc[i][2]);
            acc[i][2] = mf(aY[i], bHi[1], acc[i][2]);
            acc[i][3] = mf(aX[i], bHi[2], acc[i][3]);
            acc[i][3] = mf(aY[i], bHi[3], acc[i][3]);
        }
#pragma unroll
        for (int i = 0; i < 4; ++i) {
            aX[i] = *(const bf16x8*)&As[cb + 8192 + i * 1024 + aB0];
            aY[i] = *(const bf16x8*)&As[cb + 8192 + i * 1024 + aB1];
        }
#pragma unroll
        for (int i = 0; i < 4; ++i) {
            acc[4 + i][0] = mf(aX[i], bLo[0], acc[4 + i][0]);
            acc[4 + i][0] = mf(aY[i], bLo[1], acc[4 + i][0]);
            acc[4 + i][1] = mf(aX[i], bLo[2], acc[4 + i][1]);
            acc[4 + i][1] = mf(aY[i], bLo[3], acc[4 + i][1]);
            acc[4 + i][2] = mf(aX[i], bHi[0], acc[4 + i][2]);
            acc[4 + i][2] = mf(aY[i], bHi[1], acc[4 + i][2]);
            acc[4 + i][3] = mf(aX[i], bHi[2], acc[4 + i][3]);
            acc[4 + i][3] = mf(aY[i], bHi[3], acc[4 + i][3]);
        }
    }

    // ---- epilogue C-write (C/D map: col=l16, row=q*4+reg) ----------------
#pragma unroll
    for (int fm = 0; fm < 8; ++fm) {
#pragma unroll
        for (int rg = 0; rg < 4; ++rg) {
            const int row = by * 256 + wm * 128 + fm * 16 + q * 4 + rg;
            u16* yp = Y + (size_t)row * NN + bx * 256 + wn * 64 + l16;
#pragma unroll
            for (int fn = 0; fn < 4; ++fn) yp[fn * 16] = f2b(acc[fm][fn][rg]);
        }
    }
}

// ---- K2: rowwise LN(2048)+sigmoid -> FN=(f,nd) packed, R -----------------
// Raw s_barrier (no vmcnt drain): xt load issued early stays in flight.
__global__ __launch_bounds__(256) void k_lnsig(const u16* __restrict__ Y,
                                               const float* __restrict__ bg,
                                               const float* __restrict__ gg,
                                               const float* __restrict__ bt,
                                               uint32_t* __restrict__ FN,
                                               u16* __restrict__ R) {
    const int row = blockIdx.x;
    const int t = threadIdx.x;
    const u16* yr = Y + (size_t)row * 3072;
    us8 gv = *(const us8*)(yr + 1024 + t * 8);
    us8 xt;
    if (t < 128) xt = *(const us8*)(yr + t * 8);   // issue early, in flight
    float z[8];
    float s = 0.f, s2 = 0.f;
#pragma unroll
    for (int k = 0; k < 8; k++) {
        z[k] = b2f(gv[k]) + bg[t * 8 + k];
        s += z[k];
        s2 += z[k] * z[k];
    }
#pragma unroll
    for (int m = 1; m < 64; m <<= 1) {
        s += __shfl_xor(s, m);
        s2 += __shfl_xor(s2, m);
    }
    __shared__ float red[8];
    if ((t & 63) == 0) { red[t >> 6] = s; red[(t >> 6) + 4] = s2; }
    asm volatile("s_waitcnt lgkmcnt(0)" ::: "memory");
    __builtin_amdgcn_sched_barrier(0);
    __builtin_amdgcn_s_barrier();
    MEMBAR();
    s = red[0] + red[1] + red[2] + red[3];
    s2 = red[4] + red[5] + red[6] + red[7];
    const float mu = s * (1.f / 2048.f);
    const float inv = rsqrtf(s2 * (1.f / 2048.f) - mu * mu + 1e-5f);
    float gate[8];
#pragma unroll
    for (int k = 0; k < 8; k++)
        gate[k] = sigm((z[k] - mu) * inv * gg[t * 8 + k] + bt[t * 8 + k]);
    if (t < 128) {
        u32x8 fn;
#pragma unroll
        for (int k = 0; k < 8; k++) {
            u16 fb = f2b(gate[k]);
            u16 nb = f2b((1.f - gate[k]) * b2f(xt[k]));
            fn[k] = (uint32_t)fb | ((uint32_t)nb << 16);
        }
        *(u32x8*)(FN + (size_t)row * 1024 + t * 8) = fn;
    } else {
        us8 ro;
#pragma unroll
        for (int k = 0; k < 8; k++) ro[k] = f2b(gate[k]);
        *(us8*)(R + (size_t)row * 1024 + (t - 128) * 8) = ro;
    }
}

// ---- K3: scan pass 1 — per-(b,h,chunk) aggregates, 2 h per thread --------
__global__ __launch_bounds__(256) void k_scan1(const uint32_t* __restrict__ FN,
                                               float2* __restrict__ agg) {
    int u = blockIdx.x * 256 + threadIdx.x;   // 262144
    int h2 = u & 511;                          // h = 2*h2
    int chunk = (u >> 9) & 31;
    int b = u >> 14;
    size_t base = (size_t)(b * 2048 + chunk * 64) * 1024 + h2 * 2;
    float F0 = 1.f, N0 = 0.f, F1 = 1.f, N1 = 0.f;
#pragma unroll 8
    for (int i = 0; i < 64; i++) {
        uint2 v = *(const uint2*)(FN + base + (size_t)i * 1024);
        float f0 = b2f((u16)(v.x & 0xffffu)), n0 = b2f((u16)(v.x >> 16));
        float f1 = b2f((u16)(v.y & 0xffffu)), n1 = b2f((u16)(v.y >> 16));
        N0 = fmaf(f0, N0, n0); F0 *= f0;
        N1 = fmaf(f1, N1, n1); F1 *= f1;
    }
    float4 o = {F0, N0, F1, N1};
    *(float4*)&agg[(size_t)(b * 32 + chunk) * 1024 + h2 * 2] = o;
}

// ---- K4: scan over chunk aggregates -> per-chunk prefix P [b][chunk][h] --
__global__ __launch_bounds__(256) void k_scan2(const float2* __restrict__ agg,
                                               const float* __restrict__ c0,
                                               float* __restrict__ P) {
    int u = blockIdx.x * 256 + threadIdx.x;  // (b*1024+h), 16384 total
    int b = u >> 10, h = u & 1023;
    float c = c0[u];
#pragma unroll 8
    for (int k = 0; k < 32; k++) {
        size_t idx = (size_t)(b * 32 + k) * 1024 + h;
        P[idx] = c;
        float2 fn = agg[idx];
        c = fmaf(fn.x, c, fn.y);
    }
}

// ---- K5: fused scan pass 2 + LN_h + output h (no C materialization) ------
// Raw s_barrier per iter (no vmcnt drain); depth-2 named-set prefetch of
// FN/R/xb so global loads stay in flight across barriers.
#define SOUT_STEP(fnv, rvv, xvv, ro, p)                                        \
    {                                                                          \
        c0 = fmaf(b2f((u16)((fnv).x & 0xffffu)), c0, b2f((u16)((fnv).x >> 16)));\
        c1 = fmaf(b2f((u16)((fnv).y & 0xffffu)), c1, b2f((u16)((fnv).y >> 16)));\
        float s = c0 + c1, s2 = c0 * c0 + c1 * c1;                             \
        _Pragma("unroll")                                                      \
        for (int m = 1; m < 64; m <<= 1) {                                     \
            s += __shfl_xor(s, m);                                             \
            s2 += __shfl_xor(s2, m);                                           \
        }                                                                      \
        if (lane == 0) red[p][w] = make_float2(s, s2);                         \
        asm volatile("s_waitcnt lgkmcnt(0)" ::: "memory");                     \
        __builtin_amdgcn_sched_barrier(0);                                     \
        __builtin_amdgcn_s_barrier();                                          \
        MEMBAR();                                                              \
        s = 0.f; s2 = 0.f;                                                     \
        _Pragma("unroll")                                                      \
        for (int k = 0; k < 8; k++) { float2 v = red[p][k]; s += v.x; s2 += v.y; } \
        const float mu = s * (1.f / 1024.f);                                   \
        const float inv = rsqrtf(s2 * (1.f / 1024.f) - mu * mu + 1e-5f);       \
        const float sg0 = sigm((c0 - mu) * inv * g0 + be0);                    \
        const float sg1 = sigm((c1 - mu) * inv * g1 + be1);                    \
        const float r0 = b2f((u16)((rvv) & 0xffffu)), r1 = b2f((u16)((rvv) >> 16)); \
        const float x0 = b2f((u16)((xvv) & 0xffffu)), x1 = b2f((u16)((xvv) >> 16)); \
        float2 ho = {r0 * sg0 + (1.f - r0) * x0, r1 * sg1 + (1.f - r1) * x1};  \
        *(float2*)(out + (ro)) = ho;                                           \
    }

__global__ __launch_bounds__(512) void k_scanout(const uint32_t* __restrict__ FN,
                                                 const float* __restrict__ P,
                                                 const u16* __restrict__ R,
                                                 const u16* __restrict__ xb,
                                                 const float* __restrict__ ga,
                                                 const float* __restrict__ ba,
                                                 float* __restrict__ out,
                                                 float* __restrict__ cfin) {
    __shared__ float2 red[2][8];
    const int t = threadIdx.x;
    const int b = blockIdx.x >> 5, chunk = blockIdx.x & 31;
    const int h = t * 2;
    const int w = t >> 6, lane = t & 63;
    float2 cp = *(const float2*)&P[(size_t)(b * 32 + chunk) * 1024 + h];
    float c0 = cp.x, c1 = cp.y;
    const float g0 = ga[h], g1 = ga[h + 1];
    const float be0 = ba[h], be1 = ba[h + 1];
    const size_t base = (size_t)(b * 2048 + chunk * 64) * 1024 + h;

    uint2 fnA = *(const uint2*)(FN + base);
    uint32_t rvA = *(const uint32_t*)(R + base);
    uint32_t xvA = *(const uint32_t*)(xb + base);
    uint2 fnB = *(const uint2*)(FN + base + 1024);
    uint32_t rvB = *(const uint32_t*)(R + base + 1024);
    uint32_t xvB = *(const uint32_t*)(xb + base + 1024);

    for (int ii = 0; ii < 32; ++ii) {
        const size_t ro0 = base + (size_t)(2 * ii) * 1024;
        {   // even step: consume set A, prefetch i+2 into A
            uint2 fn = fnA; uint32_t rv = rvA, xv = xvA;
            if (ii < 31) {
                const size_t rn = ro0 + 2048;
                fnA = *(const uint2*)(FN + rn);
                rvA = *(const uint32_t*)(R + rn);
                xvA = *(const uint32_t*)(xb + rn);
            }
            SOUT_STEP(fn, rv, xv, ro0, 0)
        }
        {   // odd step: consume set B, prefetch i+3 into B
            uint2 fn = fnB; uint32_t rv = rvB, xv = xvB;
            if (ii < 31) {
                const size_t rn = ro0 + 3072;
                fnB = *(const uint2*)(FN + rn);
                rvB = *(const uint32_t*)(R + rn);
                xvB = *(const uint32_t*)(xb + rn);
            }
            SOUT_STEP(fn, rv, xv, ro0 + 1024, 1)
        }
    }
    if (chunk == 31) *(float2*)(cfin + b * 1024 + h) = make_float2(c0, c1);
}

extern "C" void kernel_launch(void* const* d_in, const int* in_sizes, int n_in,
                              void* d_out, int out_size, void* d_ws, size_t ws_size,
                              hipStream_t stream) {
    const float* x   = (const float*)d_in[0];
    const float* c0  = (const float*)d_in[1];
    const float* wlt = (const float*)d_in[2];
    const float* wg  = (const float*)d_in[3];
    const float* bg  = (const float*)d_in[4];
    const float* gg  = (const float*)d_in[5];
    const float* btg = (const float*)d_in[6];
    const float* ga  = (const float*)d_in[7];
    const float* ba  = (const float*)d_in[8];
    float* out = (float*)d_out;

    char* ws = (char*)d_ws;
    u16* xb      = (u16*)(ws);                  //  67,108,864 B
    u16* wb      = (u16*)(ws + 67108864);       //   6,291,456 B
    u16* y       = (u16*)(ws + 73400320);       // 201,326,592 B
    uint32_t* FN = (uint32_t*)(ws + 274726912); // 134,217,728 B
    u16* R       = (u16*)(ws + 408944640);      //  67,108,864 B
    float2* agg  = (float2*)(ws + 476053504);   //   4,194,304 B
    float* P     = (float*)(ws + 480247808);    //   2,097,152 B

    k_cvt<<<17920, 256, 0, stream>>>(x, wlt, wg, xb, wb);
    k_gemm<<<dim3(NN / 256, MM / 256), 512, 0, stream>>>(xb, wb, y);
    k_lnsig<<<32768, 256, 0, stream>>>(y, bg, gg, btg, FN, R);
    k_scan1<<<1024, 256, 0, stream>>>(FN, agg);
    k_scan2<<<64, 256, 0, stream>>>(agg, c0, P);
    k_scanout<<<512, 512, 0, stream>>>(FN, P, R, xb, ga, ba, out,
                                       out + (size_t)33554432);
}

// Round 4
// 627.458 us; speedup vs baseline: 1.0905x; 1.0078x over previous
//
#include <hip/hip_runtime.h>
#include <stdint.h>

typedef unsigned short u16;
typedef u16 us8 __attribute__((ext_vector_type(8)));
typedef uint32_t u32x8 __attribute__((ext_vector_type(8)));
typedef __bf16 bf16x8 __attribute__((ext_vector_type(8)));
typedef float f32x4 __attribute__((ext_vector_type(4)));

#define BB 16
#define TT 2048
#define HH 1024
#define MM 32768   // B*T
#define NN 3072    // H + 2H
#define KK 1024
#define NT 16      // K-tiles of 64

__device__ __forceinline__ float b2f(u16 u) {
    union { uint32_t i; float f; } v; v.i = ((uint32_t)u) << 16; return v.f;
}
__device__ __forceinline__ u16 f2b(float f) {
    union { uint32_t i; float f; } v; v.f = f;
    uint32_t r = v.i + 0x7fffu + ((v.i >> 16) & 1u);
    return (u16)(r >> 16);
}
__device__ __forceinline__ float sigm(float z) {
    return 1.f / (1.f + __expf(-z));
}
__device__ __forceinline__ void load_lds16(const u16* g, u16* l) {
    __builtin_amdgcn_global_load_lds(
        (const __attribute__((address_space(1))) void*)g,
        (__attribute__((address_space(3))) void*)l, 16, 0, 0);
}
__device__ __forceinline__ f32x4 mf(bf16x8 a, bf16x8 b, f32x4 c) {
    return __builtin_amdgcn_mfma_f32_16x16x32_bf16(a, b, c, 0, 0, 0);
}
#define MEMBAR() asm volatile("" ::: "memory")

// ---- K0: x fp32 -> bf16, [W_lt;W_g] fp32 -> bf16 (merged) ----------------
__global__ __launch_bounds__(256) void k_cvt(const float* __restrict__ x,
                                             const float* __restrict__ wlt,
                                             const float* __restrict__ wg,
                                             u16* __restrict__ xb,
                                             u16* __restrict__ wb) {
    long i = (long)(blockIdx.x * 256 + threadIdx.x) * 8;
    const float* s;
    u16* o;
    if (i < 33554432L) { s = x + i; o = xb + i; }
    else {
        long j = i - 33554432L;
        s = (j < 1048576L) ? (wlt + j) : (wg + (j - 1048576L));
        o = wb + j;
    }
    float4 a = *(const float4*)(s);
    float4 b = *(const float4*)(s + 4);
    us8 r;
    r[0] = f2b(a.x); r[1] = f2b(a.y); r[2] = f2b(a.z); r[3] = f2b(a.w);
    r[4] = f2b(b.x); r[5] = f2b(b.y); r[6] = f2b(b.z); r[7] = f2b(b.w);
    *(us8*)o = r;
}

// ---- K1: Y[32768,3072] = Xb @ Wb^T  (256x256, overlap-phase schedule) ----
// 512 thr = 8 waves (2M x 4N); BK=64; LDS 128 KiB dbuf; per-wave C 128x64.
// 4 regions per K-tile, ONE barrier each (post-MFMA release barrier only).
// No pre-MFMA barrier / lgkmcnt pins: the compiler emits counted per-use
// lgkmcnt, so ds_reads overlap MFMA within a wave, and wave skew lets
// laggards' LDS reads run under leaders' MFMA clusters. sched_barrier(0)
// before each release barrier pins MFMAs (register-only ops) from sinking
// past it (rule #18), preserving the staging-region hazard proof:
// every read is consumed by an MFMA before the release barrier; staging
// into that region is issued only after the barrier. vmcnt(8) once per
// K-tile (tile kt+1's 8 loads landed; kt+2's 8 stay in flight).
__global__ __launch_bounds__(512, 2) void k_gemm(const u16* __restrict__ A,
                                                 const u16* __restrict__ W,
                                                 u16* __restrict__ Y) {
    __shared__ u16 As[2 * 16384];
    __shared__ u16 Bs[2 * 16384];
    const int tid = threadIdx.x;
    const int lane = tid & 63;
    const int w = tid >> 6;        // 0..7
    const int wm = w >> 2;         // 0..1
    const int wn = w & 3;          // 0..3
    const int q = lane >> 4;
    const int l16 = lane & 15;

    // XCD-aware bijective swizzle: nwg=1536, 192 per XCD; consecutive sw on
    // one XCD share the A row-panel (by) -> L2 reuse.
    const unsigned bid = blockIdx.y * 12u + blockIdx.x;
    const unsigned sw = (bid & 7u) * 192u + (bid >> 3);
    const int by = sw / 12u;       // 0..127
    const int bx = sw % 12u;       // 0..11

    // staging: per-thread pre-swizzled global source, linear LDS dest.
    const int slog = ((tid & 7) ^ ((tid >> 3) & 7)) << 3;
    const u16* aS = A + (size_t)(by * 256 + (tid >> 3)) * KK + slog;
    const u16* bS = W + (size_t)(bx * 256 + ((tid >> 8) << 6) + ((tid >> 3) & 31)) * KK + slog;
    u16* aD = As + w * 512;
    u16* bD = Bs + w * 512;

    // prologue: stage kt0 -> buf0, kt1 -> buf1
    load_lds16(aS,                aD);
    load_lds16(aS + 128 * KK,     aD + 4096);
    load_lds16(aS + 64 * KK,      aD + 8192);
    load_lds16(aS + 192 * KK,     aD + 12288);
    load_lds16(bS,                bD);
    load_lds16(bS + 128 * KK,     bD + 4096);
    load_lds16(bS + 32 * KK,      bD + 8192);
    load_lds16(bS + 160 * KK,     bD + 12288);
    load_lds16(aS + 64,           aD + 16384);
    load_lds16(aS + 64 + 128*KK,  aD + 16384 + 4096);
    load_lds16(aS + 64 + 64*KK,   aD + 16384 + 8192);
    load_lds16(aS + 64 + 192*KK,  aD + 16384 + 12288);
    load_lds16(bS + 64,           bD + 16384);
    load_lds16(bS + 64 + 128*KK,  bD + 16384 + 4096);
    load_lds16(bS + 64 + 32*KK,   bD + 16384 + 8192);
    load_lds16(bS + 64 + 160*KK,  bD + 16384 + 12288);

    // ds_read lane bases (swizzled): slot(ks) = ((ks<<2)|q) ^ (l16&7)
    const int key = l16 & 7;
    const int sA0 = ((q ^ key) << 3);
    const int sA1 = (((q ^ key) ^ 4) << 3);
    const int aB0 = wm * 4096 + l16 * 64 + sA0;   // ks0
    const int aB1 = wm * 4096 + l16 * 64 + sA1;   // ks1
    const int bB0 = wn * 2048 + l16 * 64 + sA0;
    const int bB1 = wn * 2048 + l16 * 64 + sA1;

    f32x4 zero = {0.f, 0.f, 0.f, 0.f};
    f32x4 acc[8][4];
#pragma unroll
    for (int i = 0; i < 8; ++i)
#pragma unroll
        for (int j = 0; j < 4; ++j) acc[i][j] = zero;
    bf16x8 aX[4], aY[4], bLo[4], bHi[4];

    asm volatile("s_waitcnt vmcnt(8)" ::: "memory");   // kt0 landed; kt1 in flight
    __builtin_amdgcn_sched_barrier(0);
    __builtin_amdgcn_s_barrier();
    MEMBAR();

    for (int kt = 0; kt < NT - 1; ++kt) {
        const int cb = (kt & 1) << 14;
        const int kc = (kt + 2) << 6;
        const bool st = (kt < NT - 2);
        // ===== region 1: reads Blo(4)+A0(8); MFMA q(m0,nLo) ===============
        bLo[0] = *(const bf16x8*)&Bs[cb + bB0];
        bLo[1] = *(const bf16x8*)&Bs[cb + bB1];
        bLo[2] = *(const bf16x8*)&Bs[cb + 1024 + bB0];
        bLo[3] = *(const bf16x8*)&Bs[cb + 1024 + bB1];
#pragma unroll
        for (int i = 0; i < 4; ++i) {
            aX[i] = *(const bf16x8*)&As[cb + i * 1024 + aB0];
            aY[i] = *(const bf16x8*)&As[cb + i * 1024 + aB1];
        }
        __builtin_amdgcn_s_setprio(1);
#pragma unroll
        for (int i = 0; i < 4; ++i) {
            acc[i][0] = mf(aX[i], bLo[0], acc[i][0]);
            acc[i][0] = mf(aY[i], bLo[1], acc[i][0]);
            acc[i][1] = mf(aX[i], bLo[2], acc[i][1]);
            acc[i][1] = mf(aY[i], bLo[3], acc[i][1]);
        }
        __builtin_amdgcn_s_setprio(0);
        __builtin_amdgcn_sched_barrier(0);
        MEMBAR();
        __builtin_amdgcn_s_barrier();   // release A0 + Blo regions of cb
        MEMBAR();
        if (st) {
            load_lds16(aS + kc,            aD + cb);
            load_lds16(aS + kc + 128*KK,   aD + cb + 4096);
            load_lds16(bS + kc,            bD + cb);
            load_lds16(bS + kc + 128*KK,   bD + cb + 4096);
        }
        // ===== region 2: reads Bhi(4); MFMA q(m0,nHi) =====================
        bHi[0] = *(const bf16x8*)&Bs[cb + 8192 + bB0];
        bHi[1] = *(const bf16x8*)&Bs[cb + 8192 + bB1];
        bHi[2] = *(const bf16x8*)&Bs[cb + 8192 + 1024 + bB0];
        bHi[3] = *(const bf16x8*)&Bs[cb + 8192 + 1024 + bB1];
        __builtin_amdgcn_s_setprio(1);
#pragma unroll
        for (int i = 0; i < 4; ++i) {
            acc[i][2] = mf(aX[i], bHi[0], acc[i][2]);
            acc[i][2] = mf(aY[i], bHi[1], acc[i][2]);
            acc[i][3] = mf(aX[i], bHi[2], acc[i][3]);
            acc[i][3] = mf(aY[i], bHi[3], acc[i][3]);
        }
        __builtin_amdgcn_s_setprio(0);
        __builtin_amdgcn_sched_barrier(0);
        MEMBAR();
        __builtin_amdgcn_s_barrier();   // release B-hi region of cb
        MEMBAR();
        if (st) {
            load_lds16(bS + kc + 32*KK,    bD + cb + 8192);
            load_lds16(bS + kc + 160*KK,   bD + cb + 12288);
        }
        // ===== region 3: reads A1(8); MFMA q(m1,nLo) ======================
#pragma unroll
        for (int i = 0; i < 4; ++i) {
            aX[i] = *(const bf16x8*)&As[cb + 8192 + i * 1024 + aB0];
            aY[i] = *(const bf16x8*)&As[cb + 8192 + i * 1024 + aB1];
        }
        __builtin_amdgcn_s_setprio(1);
#pragma unroll
        for (int i = 0; i < 4; ++i) {
            acc[4 + i][0] = mf(aX[i], bLo[0], acc[4 + i][0]);
            acc[4 + i][0] = mf(aY[i], bLo[1], acc[4 + i][0]);
            acc[4 + i][1] = mf(aX[i], bLo[2], acc[4 + i][1]);
            acc[4 + i][1] = mf(aY[i], bLo[3], acc[4 + i][1]);
        }
        __builtin_amdgcn_s_setprio(0);
        __builtin_amdgcn_sched_barrier(0);
        MEMBAR();
        __builtin_amdgcn_s_barrier();   // release A1 region of cb
        MEMBAR();
        if (st) {
            load_lds16(aS + kc + 64*KK,    aD + cb + 8192);
            load_lds16(aS + kc + 192*KK,   aD + cb + 12288);
        }
        // ===== region 4: MFMA q(m1,nHi); vmcnt; publish kt+1 ==============
        __builtin_amdgcn_s_setprio(1);
#pragma unroll
        for (int i = 0; i < 4; ++i) {
            acc[4 + i][2] = mf(aX[i], bHi[0], acc[4 + i][2]);
            acc[4 + i][2] = mf(aY[i], bHi[1], acc[4 + i][2]);
            acc[4 + i][3] = mf(aX[i], bHi[2], acc[4 + i][3]);
            acc[4 + i][3] = mf(aY[i], bHi[3], acc[4 + i][3]);
        }
        __builtin_amdgcn_s_setprio(0);
        if (st) { asm volatile("s_waitcnt vmcnt(8)" ::: "memory"); }
        else    { asm volatile("s_waitcnt vmcnt(0)" ::: "memory"); }
        __builtin_amdgcn_sched_barrier(0);
        MEMBAR();
        __builtin_amdgcn_s_barrier();   // publish buf(kt+1)
        MEMBAR();
    }

    // ===== peeled tile 15 (buf1; no staging, no barriers needed) ==========
    {
        const int cb = 16384;
        bLo[0] = *(const bf16x8*)&Bs[cb + bB0];
        bLo[1] = *(const bf16x8*)&Bs[cb + bB1];
        bLo[2] = *(const bf16x8*)&Bs[cb + 1024 + bB0];
        bLo[3] = *(const bf16x8*)&Bs[cb + 1024 + bB1];
        bHi[0] = *(const bf16x8*)&Bs[cb + 8192 + bB0];
        bHi[1] = *(const bf16x8*)&Bs[cb + 8192 + bB1];
        bHi[2] = *(const bf16x8*)&Bs[cb + 8192 + 1024 + bB0];
        bHi[3] = *(const bf16x8*)&Bs[cb + 8192 + 1024 + bB1];
#pragma unroll
        for (int i = 0; i < 4; ++i) {
            aX[i] = *(const bf16x8*)&As[cb + i * 1024 + aB0];
            aY[i] = *(const bf16x8*)&As[cb + i * 1024 + aB1];
        }
#pragma unroll
        for (int i = 0; i < 4; ++i) {
            acc[i][0] = mf(aX[i], bLo[0], acc[i][0]);
            acc[i][0] = mf(aY[i], bLo[1], acc[i][0]);
            acc[i][1] = mf(aX[i], bLo[2], acc[i][1]);
            acc[i][1] = mf(aY[i], bLo[3], acc[i][1]);
            acc[i][2] = mf(aX[i], bHi[0], acc[i][2]);
            acc[i][2] = mf(aY[i], bHi[1], acc[i][2]);
            acc[i][3] = mf(aX[i], bHi[2], acc[i][3]);
            acc[i][3] = mf(aY[i], bHi[3], acc[i][3]);
        }
#pragma unroll
        for (int i = 0; i < 4; ++i) {
            aX[i] = *(const bf16x8*)&As[cb + 8192 + i * 1024 + aB0];
            aY[i] = *(const bf16x8*)&As[cb + 8192 + i * 1024 + aB1];
        }
#pragma unroll
        for (int i = 0; i < 4; ++i) {
            acc[4 + i][0] = mf(aX[i], bLo[0], acc[4 + i][0]);
            acc[4 + i][0] = mf(aY[i], bLo[1], acc[4 + i][0]);
            acc[4 + i][1] = mf(aX[i], bLo[2], acc[4 + i][1]);
            acc[4 + i][1] = mf(aY[i], bLo[3], acc[4 + i][1]);
            acc[4 + i][2] = mf(aX[i], bHi[0], acc[4 + i][2]);
            acc[4 + i][2] = mf(aY[i], bHi[1], acc[4 + i][2]);
            acc[4 + i][3] = mf(aX[i], bHi[2], acc[4 + i][3]);
            acc[4 + i][3] = mf(aY[i], bHi[3], acc[4 + i][3]);
        }
    }

    // ---- epilogue C-write (C/D map: col=l16, row=q*4+reg) ----------------
#pragma unroll
    for (int fm = 0; fm < 8; ++fm) {
#pragma unroll
        for (int rg = 0; rg < 4; ++rg) {
            const int row = by * 256 + wm * 128 + fm * 16 + q * 4 + rg;
            u16* yp = Y + (size_t)row * NN + bx * 256 + wn * 64 + l16;
#pragma unroll
            for (int fn = 0; fn < 4; ++fn) yp[fn * 16] = f2b(acc[fm][fn][rg]);
        }
    }
}

// ---- K2: rowwise LN(2048)+sigmoid -> FN=(f,nd) packed, R -----------------
// Raw s_barrier (no vmcnt drain): xt load issued early stays in flight.
__global__ __launch_bounds__(256) void k_lnsig(const u16* __restrict__ Y,
                                               const float* __restrict__ bg,
                                               const float* __restrict__ gg,
                                               const float* __restrict__ bt,
                                               uint32_t* __restrict__ FN,
                                               u16* __restrict__ R) {
    const int row = blockIdx.x;
    const int t = threadIdx.x;
    const u16* yr = Y + (size_t)row * 3072;
    us8 gv = *(const us8*)(yr + 1024 + t * 8);
    us8 xt;
    if (t < 128) xt = *(const us8*)(yr + t * 8);   // issue early, in flight
    float z[8];
    float s = 0.f, s2 = 0.f;
#pragma unroll
    for (int k = 0; k < 8; k++) {
        z[k] = b2f(gv[k]) + bg[t * 8 + k];
        s += z[k];
        s2 += z[k] * z[k];
    }
#pragma unroll
    for (int m = 1; m < 64; m <<= 1) {
        s += __shfl_xor(s, m);
        s2 += __shfl_xor(s2, m);
    }
    __shared__ float red[8];
    if ((t & 63) == 0) { red[t >> 6] = s; red[(t >> 6) + 4] = s2; }
    asm volatile("s_waitcnt lgkmcnt(0)" ::: "memory");
    __builtin_amdgcn_sched_barrier(0);
    __builtin_amdgcn_s_barrier();
    MEMBAR();
    s = red[0] + red[1] + red[2] + red[3];
    s2 = red[4] + red[5] + red[6] + red[7];
    const float mu = s * (1.f / 2048.f);
    const float inv = rsqrtf(s2 * (1.f / 2048.f) - mu * mu + 1e-5f);
    float gate[8];
#pragma unroll
    for (int k = 0; k < 8; k++)
        gate[k] = sigm((z[k] - mu) * inv * gg[t * 8 + k] + bt[t * 8 + k]);
    if (t < 128) {
        u32x8 fn;
#pragma unroll
        for (int k = 0; k < 8; k++) {
            u16 fb = f2b(gate[k]);
            u16 nb = f2b((1.f - gate[k]) * b2f(xt[k]));
            fn[k] = (uint32_t)fb | ((uint32_t)nb << 16);
        }
        *(u32x8*)(FN + (size_t)row * 1024 + t * 8) = fn;
    } else {
        us8 ro;
#pragma unroll
        for (int k = 0; k < 8; k++) ro[k] = f2b(gate[k]);
        *(us8*)(R + (size_t)row * 1024 + (t - 128) * 8) = ro;
    }
}

// ---- K3: scan pass 1 — per-(b,h,chunk) aggregates, 2 h per thread --------
__global__ __launch_bounds__(256) void k_scan1(const uint32_t* __restrict__ FN,
                                               float2* __restrict__ agg) {
    int u = blockIdx.x * 256 + threadIdx.x;   // 262144
    int h2 = u & 511;                          // h = 2*h2
    int chunk = (u >> 9) & 31;
    int b = u >> 14;
    size_t base = (size_t)(b * 2048 + chunk * 64) * 1024 + h2 * 2;
    float F0 = 1.f, N0 = 0.f, F1 = 1.f, N1 = 0.f;
#pragma unroll 8
    for (int i = 0; i < 64; i++) {
        uint2 v = *(const uint2*)(FN + base + (size_t)i * 1024);
        float f0 = b2f((u16)(v.x & 0xffffu)), n0 = b2f((u16)(v.x >> 16));
        float f1 = b2f((u16)(v.y & 0xffffu)), n1 = b2f((u16)(v.y >> 16));
        N0 = fmaf(f0, N0, n0); F0 *= f0;
        N1 = fmaf(f1, N1, n1); F1 *= f1;
    }
    float4 o = {F0, N0, F1, N1};
    *(float4*)&agg[(size_t)(b * 32 + chunk) * 1024 + h2 * 2] = o;
}

// ---- K4: scan over chunk aggregates -> per-chunk prefix P [b][chunk][h] --
__global__ __launch_bounds__(256) void k_scan2(const float2* __restrict__ agg,
                                               const float* __restrict__ c0,
                                               float* __restrict__ P) {
    int u = blockIdx.x * 256 + threadIdx.x;  // (b*1024+h), 16384 total
    int b = u >> 10, h = u & 1023;
    float c = c0[u];
#pragma unroll 8
    for (int k = 0; k < 32; k++) {
        size_t idx = (size_t)(b * 32 + k) * 1024 + h;
        P[idx] = c;
        float2 fn = agg[idx];
        c = fmaf(fn.x, c, fn.y);
    }
}

// ---- K5: fused scan pass 2 + LN_h + output h (no C materialization) ------
// Raw s_barrier per iter (no vmcnt drain); depth-2 named-set prefetch of
// FN/R/xb so global loads stay in flight across barriers.
#define SOUT_STEP(fnv, rvv, xvv, ro, p)                                        \
    {                                                                          \
        c0 = fmaf(b2f((u16)((fnv).x & 0xffffu)), c0, b2f((u16)((fnv).x >> 16)));\
        c1 = fmaf(b2f((u16)((fnv).y & 0xffffu)), c1, b2f((u16)((fnv).y >> 16)));\
        float s = c0 + c1, s2 = c0 * c0 + c1 * c1;                             \
        _Pragma("unroll")                                                      \
        for (int m = 1; m < 64; m <<= 1) {                                     \
            s += __shfl_xor(s, m);                                             \
            s2 += __shfl_xor(s2, m);                                           \
        }                                                                      \
        if (lane == 0) red[p][w] = make_float2(s, s2);                         \
        asm volatile("s_waitcnt lgkmcnt(0)" ::: "memory");                     \
        __builtin_amdgcn_sched_barrier(0);                                     \
        __builtin_amdgcn_s_barrier();                                          \
        MEMBAR();                                                              \
        s = 0.f; s2 = 0.f;                                                     \
        _Pragma("unroll")                                                      \
        for (int k = 0; k < 8; k++) { float2 v = red[p][k]; s += v.x; s2 += v.y; } \
        const float mu = s * (1.f / 1024.f);                                   \
        const float inv = rsqrtf(s2 * (1.f / 1024.f) - mu * mu + 1e-5f);       \
        const float sg0 = sigm((c0 - mu) * inv * g0 + be0);                    \
        const float sg1 = sigm((c1 - mu) * inv * g1 + be1);                    \
        const float r0 = b2f((u16)((rvv) & 0xffffu)), r1 = b2f((u16)((rvv) >> 16)); \
        const float x0 = b2f((u16)((xvv) & 0xffffu)), x1 = b2f((u16)((xvv) >> 16)); \
        float2 ho = {r0 * sg0 + (1.f - r0) * x0, r1 * sg1 + (1.f - r1) * x1};  \
        *(float2*)(out + (ro)) = ho;                                           \
    }

__global__ __launch_bounds__(512) void k_scanout(const uint32_t* __restrict__ FN,
                                                 const float* __restrict__ P,
                                                 const u16* __restrict__ R,
                                                 const u16* __restrict__ xb,
                                                 const float* __restrict__ ga,
                                                 const float* __restrict__ ba,
                                                 float* __restrict__ out,
                                                 float* __restrict__ cfin) {
    __shared__ float2 red[2][8];
    const int t = threadIdx.x;
    const int b = blockIdx.x >> 5, chunk = blockIdx.x & 31;
    const int h = t * 2;
    const int w = t >> 6, lane = t & 63;
    float2 cp = *(const float2*)&P[(size_t)(b * 32 + chunk) * 1024 + h];
    float c0 = cp.x, c1 = cp.y;
    const float g0 = ga[h], g1 = ga[h + 1];
    const float be0 = ba[h], be1 = ba[h + 1];
    const size_t base = (size_t)(b * 2048 + chunk * 64) * 1024 + h;

    uint2 fnA = *(const uint2*)(FN + base);
    uint32_t rvA = *(const uint32_t*)(R + base);
    uint32_t xvA = *(const uint32_t*)(xb + base);
    uint2 fnB = *(const uint2*)(FN + base + 1024);
    uint32_t rvB = *(const uint32_t*)(R + base + 1024);
    uint32_t xvB = *(const uint32_t*)(xb + base + 1024);

    for (int ii = 0; ii < 32; ++ii) {
        const size_t ro0 = base + (size_t)(2 * ii) * 1024;
        {   // even step: consume set A, prefetch i+2 into A
            uint2 fn = fnA; uint32_t rv = rvA, xv = xvA;
            if (ii < 31) {
                const size_t rn = ro0 + 2048;
                fnA = *(const uint2*)(FN + rn);
                rvA = *(const uint32_t*)(R + rn);
                xvA = *(const uint32_t*)(xb + rn);
            }
            SOUT_STEP(fn, rv, xv, ro0, 0)
        }
        {   // odd step: consume set B, prefetch i+3 into B
            uint2 fn = fnB; uint32_t rv = rvB, xv = xvB;
            if (ii < 31) {
                const size_t rn = ro0 + 3072;
                fnB = *(const uint2*)(FN + rn);
                rvB = *(const uint32_t*)(R + rn);
                xvB = *(const uint32_t*)(xb + rn);
            }
            SOUT_STEP(fn, rv, xv, ro0 + 1024, 1)
        }
    }
    if (chunk == 31) *(float2*)(cfin + b * 1024 + h) = make_float2(c0, c1);
}

extern "C" void kernel_launch(void* const* d_in, const int* in_sizes, int n_in,
                              void* d_out, int out_size, void* d_ws, size_t ws_size,
                              hipStream_t stream) {
    const float* x   = (const float*)d_in[0];
    const float* c0  = (const float*)d_in[1];
    const float* wlt = (const float*)d_in[2];
    const float* wg  = (const float*)d_in[3];
    const float* bg  = (const float*)d_in[4];
    const float* gg  = (const float*)d_in[5];
    const float* btg = (const float*)d_in[6];
    const float* ga  = (const float*)d_in[7];
    const float* ba  = (const float*)d_in[8];
    float* out = (float*)d_out;

    char* ws = (char*)d_ws;
    u16* xb      = (u16*)(ws);                  //  67,108,864 B
    u16* wb      = (u16*)(ws + 67108864);       //   6,291,456 B
    u16* y       = (u16*)(ws + 73400320);       // 201,326,592 B
    uint32_t* FN = (uint32_t*)(ws + 274726912); // 134,217,728 B
    u16* R       = (u16*)(ws + 408944640);      //  67,108,864 B
    float2* agg  = (float2*)(ws + 476053504);   //   4,194,304 B
    float* P     = (float*)(ws + 480247808);    //   2,097,152 B

    k_cvt<<<17920, 256, 0, stream>>>(x, wlt, wg, xb, wb);
    k_gemm<<<dim3(NN / 256, MM / 256), 512, 0, stream>>>(xb, wb, y);
    k_lnsig<<<32768, 256, 0, stream>>>(y, bg, gg, btg, FN, R);
    k_scan1<<<1024, 256, 0, stream>>>(FN, agg);
    k_scan2<<<64, 256, 0, stream>>>(agg, c0, P);
    k_scanout<<<512, 512, 0, stream>>>(FN, P, R, xb, ga, ba, out,
                                       out + (size_t)33554432);
}